// Round 8
// baseline (1004.828 us; speedup 1.0000x reference)
//
#include <hip/hip_runtime.h>
#include <cstdint>
#include <cstddef>

// Problem constants (from reference)
#define OUT_F 4096
#define IN_F  11008
#define VECD  8
#define NVEC  (OUT_F * IN_F / VECD)   // 5,636,096 vectors
#define VPR   (IN_F / VECD)           // 1376 vectors per output row
#define NCODES 32768
#define M_DIM 4096                    // 2*2048 flattened batch*seq
#define N_DIM OUT_F
#define K_DIM IN_F

typedef __attribute__((ext_vector_type(4))) float f32x4;
typedef __attribute__((ext_vector_type(8))) __bf16 bf16x8;
typedef __attribute__((ext_vector_type(4))) unsigned int u32x4;

__device__ inline unsigned short f2bf(float f) {     // RNE
  union { float f; unsigned int u; } v; v.f = f;
  unsigned int u = v.u;
  unsigned int r = u + 0x7FFFu + ((u >> 16) & 1u);
  return (unsigned short)(r >> 16);
}

// ---------------------------------------------------------------------------
// Phase 0: pre-cast codebook fp32 -> bf16 once (512 KB out, ~3 µs).
// C = s[n] * (X @ W0^T): scale factored into the GEMM epilogue (r11, passed).
// ---------------------------------------------------------------------------
__global__ __launch_bounds__(256) void cbcast_kernel(
    const float* __restrict__ cb, unsigned short* __restrict__ cbb) {
  int i = blockIdx.x * 256 + threadIdx.x;
  if (i >= NCODES) return;
  const f32x4* c = (const f32x4*)(cb + (size_t)i * VECD);
  f32x4 c0 = c[0], c1 = c[1];
  u32x4 w;
  w.x = (unsigned)f2bf(c0.x) | ((unsigned)f2bf(c0.y) << 16);
  w.y = (unsigned)f2bf(c0.z) | ((unsigned)f2bf(c0.w) << 16);
  w.z = (unsigned)f2bf(c1.x) | ((unsigned)f2bf(c1.y) << 16);
  w.w = (unsigned)f2bf(c1.z) | ((unsigned)f2bf(c1.w) << 16);
  *(u32x4*)(cbb + (size_t)i * 8) = w;
}

// ---------------------------------------------------------------------------
// Phase 1: X fp32 -> bf16 cast ONLY.  Round-12: the W path is FUSED into the
// GEMM (wb eliminated).  Rationale: phase-1 sat at ~280 µs across FIVE
// different implementations (r0/r2/r3/r6/r7) incl. a trivial gather-copy,
// defying every throughput model (roofline 61 µs) — so the W materialization
// is deleted rather than optimized.  total − gemm − 3 now isolates xcast
// exactly, settling the decomposition mystery either way.
// ---------------------------------------------------------------------------
__global__ __launch_bounds__(256) void xcast_kernel(
    const float* __restrict__ x, unsigned short* __restrict__ xb) {
  const unsigned stride = gridDim.x * 256;
  for (unsigned v = blockIdx.x * 256 + threadIdx.x; v < NVEC; v += stride) {
    const f32x4* xp = (const f32x4*)(x + (size_t)v * 8);
    f32x4 x0 = xp[0], x1 = xp[1];
    u32x4 q;
    q.x = (unsigned)f2bf(x0.x) | ((unsigned)f2bf(x0.y) << 16);
    q.y = (unsigned)f2bf(x0.z) | ((unsigned)f2bf(x0.w) << 16);
    q.z = (unsigned)f2bf(x1.x) | ((unsigned)f2bf(x1.y) << 16);
    q.w = (unsigned)f2bf(x1.z) | ((unsigned)f2bf(x1.w) << 16);
    *(u32x4*)(xb + (size_t)v * 8) = q;
  }
}

// ---------------------------------------------------------------------------
// Phase 2 (FUSED): C[M,N] = s[n] * (A[M,K] @ gather(cbb, idx)[N,K]^T)
//
// Geometry/MFMA/read-swizzle/epilogue = the proven 342 µs kernel.  B-staging
// replaced: each 16B B-chunk IS one codebook vector, so per K-step thread t
// does {2 idx loads, 2 16B gathers (512KB L2-resident cbb), 2 ds_write_b128}
// into the SAME LDS slots the old GLD16 produced (reg-staged path; read side
// unchanged).  B-feed drops 1.44 GB bf16 -> 360 MB idx + L2 gathers.
//
// T14 pipeline, explicit vmcnt bookkeeping (issue order per iter t):
//   prior iters left outstanding: A(t)2 < idx(t+2)2 < g(t+1)2 < A(t+1)2
//   step1  vmcnt(6)+lgkmcnt(0); barrier   -> retires A(t): tile t complete
//   step2  load idx(t+3) x2
//   step3  gather g(t+2) x2  (compiler auto-wait retires idx(t+2))
//   step4  vmcnt(6)                       -> retires g(t+1)
//   step5  ds_write B(t+1) -> SB[(t+1)%3]  (buf free since barrier t-1)
//   step6  GLD16 A(t+2)    -> SA[(t+2)%3]  (buf free since step1 barrier)
//   step7  ds_read frags from buf t%3; 32x MFMA
// leaving A(t+1)2 < idx(t+3)2 < g(t+2)2 < A(t+2)2 — induction holds.
// asm "memory" clobbers pin load groups across the waits; sched_barrier(0)
// pins the prologue issue order.  Tail: clamped redundant fetches/writes
// (never read) keep counts uniform, as in the verified baseline.
// ---------------------------------------------------------------------------
#define GLD16(g, l)                                                     \
  __builtin_amdgcn_global_load_lds(                                     \
      (const __attribute__((address_space(1))) void*)(g),               \
      (__attribute__((address_space(3))) void*)(l), 16, 0, 0)

__global__ __launch_bounds__(512, 2) void gemm_bt_kernel(
    const unsigned short* __restrict__ A,   // M x K bf16 (X)
    const int* __restrict__ IDX,            // N x VPR int32 codebook indices
    const unsigned short* __restrict__ cbb, // NCODES x 8 bf16 codebook
    const float* __restrict__ S,            // N fp32 row scales
    float* __restrict__ C) {                // M x N fp32
  extern __shared__ unsigned short SMEM[];  // 3*(8192+8192) = 96 KB
  unsigned short* SA = SMEM;                // [3][8192]
  unsigned short* SB = SMEM + 3 * 8192;     // [3][8192]

  const int tid  = threadIdx.x;
  const int bm   = blockIdx.x >> 4;         // 0..15
  const int bn   = blockIdx.x & 15;         // 0..15
  const int lane = tid & 63;
  const int wave = tid >> 6;                // 0..7
  const int wm   = (wave & 1) * 128;        // 2 waves in M
  const int wn   = (wave >> 1) * 64;        // 4 waves in N
  const int lrow = lane & 15;
  const int kgrp = lane >> 4;
  const int kslot = (kgrp ^ ((lrow >> 1) & 3)) * 8;

  // LDS slot ownership (unchanged): thread t owns 16B chunks at l0 (row t>>2)
  // and l1 (row t>>2 + 128); source chunk index cg = (t&3)^((row>>1)&3).
  const int srow = tid >> 2;                // 0..127
  const int cg   = (tid & 3) ^ ((srow >> 1) & 3);
  const unsigned short* a0 = A + (size_t)(bm * 256 + srow) * K_DIM + cg * 8;
  const unsigned short* a1 = a0 + (size_t)128 * K_DIM;
  const int l0 = tid * 8;                   // rows 0..127 region
  const int l1 = 4096 + tid * 8;            // rows 128..255 region

  // B gather addressing: vector index of (row, k-chunk) = row*VPR + kf/8 + cg.
  const size_t ivA = (size_t)(bn * 256 + srow) * VPR + cg;
  const size_t ivB = ivA + (size_t)128 * VPR;

  f32x4 acc[8][4];
#pragma unroll
  for (int i = 0; i < 8; i++)
#pragma unroll
    for (int j = 0; j < 4; j++) acc[i][j] = f32x4{0.f, 0.f, 0.f, 0.f};

  // ---- Prologue: pin issue order so steady-state vmcnt counts hold ----
  int i0a = IDX[ivA];      int i0b = IDX[ivB];        // idx(0)
  int i1a = IDX[ivA + 4];  int i1b = IDX[ivB + 4];    // idx(1)
  __builtin_amdgcn_sched_barrier(0);
  u32x4 g0a = *(const u32x4*)(cbb + (size_t)i0a * 8); // g(0)
  u32x4 g0b = *(const u32x4*)(cbb + (size_t)i0b * 8);
  __builtin_amdgcn_sched_barrier(0);
  GLD16(a0, &SA[l0]);  GLD16(a1, &SA[l1]);            // A(0) -> buf0
  __builtin_amdgcn_sched_barrier(0);
  u32x4 gcur0 = *(const u32x4*)(cbb + (size_t)i1a * 8); // g(1)
  u32x4 gcur1 = *(const u32x4*)(cbb + (size_t)i1b * 8);
  __builtin_amdgcn_sched_barrier(0);
  GLD16(a0 + 32, &SA[8192 + l0]);                     // A(1) -> buf1
  GLD16(a1 + 32, &SA[8192 + l1]);
  __builtin_amdgcn_sched_barrier(0);
  int cidx0 = IDX[ivA + 8];  int cidx1 = IDX[ivB + 8]; // idx(2)
  __builtin_amdgcn_sched_barrier(0);
  *(u32x4*)&SB[l0] = g0a;                             // B(0) -> buf0
  *(u32x4*)&SB[l1] = g0b;                             // (auto-wait g(0))
  // Outstanding now (old->new): A(0)2, g(1)2, A(1)2, idx(2)2.

  int cbuf = 0, nbuf = 1, pbuf = 2;

  for (int k0 = 0; k0 < K_DIM; k0 += 32) {
    // step1: retire A(t); B(t) ds_write drained; all waves synced.
    asm volatile("s_waitcnt vmcnt(6) lgkmcnt(0)\n\ts_barrier" ::: "memory");

    int kf2 = k0 + 64; if (kf2 > K_DIM - 32) kf2 = K_DIM - 32;  // A(t+2)
    int kf3 = k0 + 96; if (kf3 > K_DIM - 32) kf3 = K_DIM - 32;  // idx(t+3)

    int nidx0 = IDX[ivA + (kf3 >> 3)];                // step2: idx(t+3)
    int nidx1 = IDX[ivB + (kf3 >> 3)];
    u32x4 gn0 = *(const u32x4*)(cbb + (size_t)cidx0 * 8); // step3: g(t+2)
    u32x4 gn1 = *(const u32x4*)(cbb + (size_t)cidx1 * 8);

    asm volatile("s_waitcnt vmcnt(6)" ::: "memory");  // step4: retire g(t+1)

    *(u32x4*)&SB[nbuf * 8192 + l0] = gcur0;           // step5: B(t+1)
    *(u32x4*)&SB[nbuf * 8192 + l1] = gcur1;
    GLD16(a0 + kf2, &SA[pbuf * 8192 + l0]);           // step6: A(t+2)
    GLD16(a1 + kf2, &SA[pbuf * 8192 + l1]);

    bf16x8 af[8], bfr[4];                             // step7: compute tile t
#pragma unroll
    for (int i = 0; i < 8; i++)
      af[i] = *(const bf16x8*)&SA[cbuf * 8192 + (wm + i * 16 + lrow) * 32 + kslot];
#pragma unroll
    for (int j = 0; j < 4; j++)
      bfr[j] = *(const bf16x8*)&SB[cbuf * 8192 + (wn + j * 16 + lrow) * 32 + kslot];

#pragma unroll
    for (int i = 0; i < 8; i++)
#pragma unroll
      for (int j = 0; j < 4; j++)
        acc[i][j] = __builtin_amdgcn_mfma_f32_16x16x32_bf16(
            af[i], bfr[j], acc[i][j], 0, 0, 0);

    gcur0 = gn0; gcur1 = gn1;                         // rotate pipeline regs
    cidx0 = nidx0; cidx1 = nidx1;
    int old = cbuf; cbuf = nbuf; nbuf = pbuf; pbuf = old;
  }

  // Epilogue: C/D layout col = lane&15, row = (lane>>4)*4 + reg [m89-verified]
  // + factored-out per-column scale in fp32 (r11, harness-passed).
  float sj[4];
#pragma unroll
  for (int j = 0; j < 4; j++)
    sj[j] = S[bn * 256 + wn + j * 16 + lrow];

#pragma unroll
  for (int i = 0; i < 8; i++) {
    const int row0 = bm * 256 + wm + i * 16 + kgrp * 4;
#pragma unroll
    for (int j = 0; j < 4; j++) {
      const int col = bn * 256 + wn + j * 16 + lrow;
#pragma unroll
      for (int r = 0; r < 4; r++)
        C[(size_t)(row0 + r) * N_DIM + col] = acc[i][j][r] * sj[j];
    }
  }
}

// ---------------------------------------------------------------------------
// Fallback (only if workspace is too small for xb + cbb).
// ---------------------------------------------------------------------------
__global__ __launch_bounds__(256) void naive_kernel(
    const float* __restrict__ x, const int* __restrict__ indices,
    const float* __restrict__ cb, const float* __restrict__ scales,
    float* __restrict__ out) {
  int n = blockIdx.x * 256 + threadIdx.x;
  int m = blockIdx.y;
  if (n >= N_DIM) return;
  float s = scales[n];
  const float* xr = x + (size_t)m * IN_F;
  const int* ir = indices + (size_t)n * VPR;
  float acc = 0.f;
  for (int v = 0; v < VPR; v++) {
    int id = ir[v];
    const float* c = cb + (size_t)id * 8;
#pragma unroll
    for (int e = 0; e < 8; e++) acc += xr[v * 8 + e] * c[e];
  }
  out[(size_t)m * N_DIM + n] = acc * s;
}

extern "C" void kernel_launch(void* const* d_in, const int* in_sizes, int n_in,
                              void* d_out, int out_size, void* d_ws, size_t ws_size,
                              hipStream_t stream) {
  const float* x       = (const float*)d_in[0];   // (2,2048,11008) fp32
  const int*   indices = (const int*)d_in[1];     // (5636096,) int32
  const float* cb      = (const float*)d_in[2];   // (32768,8) fp32
  const float* scales  = (const float*)d_in[3];   // (4096,1) fp32
  float* out = (float*)d_out;                     // (2,2048,4096) fp32

  const size_t xb_elems  = (size_t)M_DIM * K_DIM;  // 45,088,768
  const size_t cbb_elems = (size_t)NCODES * VECD;  // 262,144
  const size_t need = (xb_elems + cbb_elems) * sizeof(unsigned short); // ~91 MB

  if (ws_size >= need) {
    unsigned short* xb  = (unsigned short*)d_ws;
    unsigned short* cbb = xb + xb_elems;
    cbcast_kernel<<<NCODES / 256, 256, 0, stream>>>(cb, cbb);
    xcast_kernel<<<2048, 256, 0, stream>>>(x, xb);
    gemm_bt_kernel<<<(M_DIM / 256) * (N_DIM / 256), 512, 6 * 8192 * 2, stream>>>(
        xb, indices, cbb, scales, out);
  } else {
    naive_kernel<<<dim3(N_DIM / 256, M_DIM), 256, 0, stream>>>(x, indices, cb,
                                                               scales, out);
  }
}

// Round 9
// 819.529 us; speedup vs baseline: 1.2261x; 1.2261x over previous
//
#include <hip/hip_runtime.h>
#include <cstdint>
#include <cstddef>

// Problem constants (from reference)
#define OUT_F 4096
#define IN_F  11008
#define VECD  8
#define NVEC  (OUT_F * IN_F / VECD)   // 5,636,096 vectors
#define VPR   (IN_F / VECD)           // 1376 vectors per output row
#define NCODES 32768
#define M_DIM 4096                    // 2*2048 flattened batch*seq
#define N_DIM OUT_F
#define K_DIM IN_F

typedef __attribute__((ext_vector_type(4))) float f32x4;
typedef __attribute__((ext_vector_type(8))) __bf16 bf16x8;
typedef __attribute__((ext_vector_type(4))) unsigned int u32x4;

__device__ inline unsigned short f2bf(float f) {     // RNE
  union { float f; unsigned int u; } v; v.f = f;
  unsigned int u = v.u;
  unsigned int r = u + 0x7FFFu + ((u >> 16) & 1u);
  return (unsigned short)(r >> 16);
}

// ---------------------------------------------------------------------------
// Phase 0: pre-cast codebook fp32 -> bf16 once (512 KB, ~3 µs).
// C = s[n] * (X @ W0^T): scale factored into the GEMM epilogue (r11, passed).
// ---------------------------------------------------------------------------
__global__ __launch_bounds__(256) void cbcast_kernel(
    const float* __restrict__ cb, unsigned short* __restrict__ cbb) {
  int i = blockIdx.x * 256 + threadIdx.x;
  if (i >= NCODES) return;
  const f32x4* c = (const f32x4*)(cb + (size_t)i * VECD);
  f32x4 c0 = c[0], c1 = c[1];
  u32x4 w;
  w.x = (unsigned)f2bf(c0.x) | ((unsigned)f2bf(c0.y) << 16);
  w.y = (unsigned)f2bf(c0.z) | ((unsigned)f2bf(c0.w) << 16);
  w.z = (unsigned)f2bf(c1.x) | ((unsigned)f2bf(c1.y) << 16);
  w.w = (unsigned)f2bf(c1.z) | ((unsigned)f2bf(c1.w) << 16);
  *(u32x4*)(cbb + (size_t)i * 8) = w;
}

// ---------------------------------------------------------------------------
// Phase 1: W gather-copy only (idx -> one 16B L2 gather -> 16B store).
// Round-13 accounting (r8's decomposition): xcast alone = ~225 µs across ALL
// five variants tried this session (1.2 TB/s, defies every model) -> xcast is
// DELETED: the GEMM now reads X fp32 and converts during A-staging.  The
// W-path stays materialized: r8 proved in-GEMM B-gather is TA request-rate
// toxic (64 random lines/wave-instr on the critical path, gemm 776 µs,
// MfmaUtil 20%).  This standalone gather-copy measured ~45-60 µs marginal.
// ---------------------------------------------------------------------------
__global__ __launch_bounds__(256) void wdequant_kernel(
    const int* __restrict__ indices, const unsigned short* __restrict__ cbb,
    unsigned short* __restrict__ wb) {
  int v = blockIdx.x * 256 + threadIdx.x;
  if (v >= NVEC) return;
  int id = indices[v];
  u32x4 w = *(const u32x4*)(cbb + (size_t)id * 8);
  *(u32x4*)(wb + (size_t)v * 8) = w;
}

// ---------------------------------------------------------------------------
// Phase 2: C[M,N] = s[n] * (cast_bf16(X)[M,K] @ B0[N,K]^T), X read as FP32.
//
// Geometry/MFMA/read-swizzle/epilogue = the proven 342 µs kernel.  B-staging
// unchanged (GLD16 from wb, 2/thread/iter).  A-staging: 4 coalesced f32x4
// loads from x (2 tiles ahead, named reg ping-pong per rule #20), f2bf
// convert (numerically identical to the old xcast), ds_write_b128 into the
// SAME LDS slots/swizzle the old GLD16 produced (cg XOR applied on the fp32
// source addresses; read side untouched).  Feed = 2.88 GB fp32 A + 1.44 GB
// bf16 B = 4.32 GB -> ~423 µs at the session-measured 10.2 TB/s feed ceiling
// (model 2-for-2: r8 256x128 predicted 414, measured 414-422).
//
// vmcnt bookkeeping (issue order pinned by sched_barrier(0)):
//   ENTER iter t outstanding (old->new): B(t)2, A(t+1)4, B(t+1)2  (=8)
//   step1  vmcnt(6) lgkmcnt(0); s_barrier  -> retires B(t); A(t) write done
//   step2  issue A(t+2) fp32 x4            -> 10
//   step3  GLD16 B(t+2) x2 -> SB[pbuf]     -> 12
//   step4  vmcnt(8)                        -> A(t+1) regs ready
//   step5  f2bf + ds_write A(t+1) -> SA[nbuf]
//   step7  ds_read frags from cbuf; 32x MFMA; rotate
//   EXIT: B(t+1)2, A(t+2)4, B(t+2)2 (=8) — induction holds.
// Tail: clamped redundant fetches/writes (never read) keep counts uniform.
// ---------------------------------------------------------------------------
#define GLD16(g, l)                                                     \
  __builtin_amdgcn_global_load_lds(                                     \
      (const __attribute__((address_space(1))) void*)(g),               \
      (__attribute__((address_space(3))) void*)(l), 16, 0, 0)

__global__ __launch_bounds__(512, 2) void gemm_bt_kernel(
    const float* __restrict__ X,            // M x K fp32 (x, read directly)
    const unsigned short* __restrict__ B,   // N x K bf16 (W0, unscaled)
    const float* __restrict__ S,            // N fp32 row scales
    float* __restrict__ C) {                // M x N fp32
  extern __shared__ unsigned short SMEM[];  // 3*(8192+8192) = 96 KB
  unsigned short* SA = SMEM;                // [3][8192]
  unsigned short* SB = SMEM + 3 * 8192;     // [3][8192]

  const int tid  = threadIdx.x;
  const int bm   = blockIdx.x >> 4;         // 0..15
  const int bn   = blockIdx.x & 15;         // 0..15
  const int lane = tid & 63;
  const int wave = tid >> 6;                // 0..7
  const int wm   = (wave & 1) * 128;        // 2 waves in M
  const int wn   = (wave >> 1) * 64;        // 4 waves in N
  const int lrow = lane & 15;
  const int kgrp = lane >> 4;
  const int kslot = (kgrp ^ ((lrow >> 1) & 3)) * 8;

  // LDS slot ownership (unchanged): thread t owns 16B chunks at l0 (row t>>2)
  // and l1 (row t>>2 + 128); source chunk index cg = (t&3)^((row>>1)&3).
  const int srow = tid >> 2;                // 0..127
  const int cg   = (tid & 3) ^ ((srow >> 1) & 3);
  const float* a0f = X + (size_t)(bm * 256 + srow) * K_DIM + cg * 8;
  const float* a1f = a0f + (size_t)128 * K_DIM;
  const unsigned short* b0 = B + (size_t)(bn * 256 + srow) * K_DIM + cg * 8;
  const unsigned short* b1 = b0 + (size_t)128 * K_DIM;
  const int l0 = tid * 8;                   // rows 0..127 region
  const int l1 = 4096 + tid * 8;            // rows 128..255 region

  f32x4 acc[8][4];
#pragma unroll
  for (int i = 0; i < 8; i++)
#pragma unroll
    for (int j = 0; j < 4; j++) acc[i][j] = f32x4{0.f, 0.f, 0.f, 0.f};

  // ---- Prologue (issue order pinned: A(0)4, B(0)2, A(1)4, B(1)2) ----
  f32x4 t0 = *(const f32x4*)(a0f);          // A(0)
  f32x4 t1 = *(const f32x4*)(a0f + 4);
  f32x4 t2 = *(const f32x4*)(a1f);
  f32x4 t3 = *(const f32x4*)(a1f + 4);
  __builtin_amdgcn_sched_barrier(0);
  GLD16(b0, &SB[l0]);  GLD16(b1, &SB[l1]);  // B(0) -> buf0
  __builtin_amdgcn_sched_barrier(0);
  f32x4 cA0 = *(const f32x4*)(a0f + 32);    // A(1) (held in regs)
  f32x4 cA1 = *(const f32x4*)(a0f + 36);
  f32x4 cA2 = *(const f32x4*)(a1f + 32);
  f32x4 cA3 = *(const f32x4*)(a1f + 36);
  __builtin_amdgcn_sched_barrier(0);
  GLD16(b0 + 32, &SB[8192 + l0]);           // B(1) -> buf1
  GLD16(b1 + 32, &SB[8192 + l1]);
  __builtin_amdgcn_sched_barrier(0);
  asm volatile("s_waitcnt vmcnt(8)" ::: "memory");   // A(0) regs ready
  {
    u32x4 w0, w1;
    w0.x = (unsigned)f2bf(t0.x) | ((unsigned)f2bf(t0.y) << 16);
    w0.y = (unsigned)f2bf(t0.z) | ((unsigned)f2bf(t0.w) << 16);
    w0.z = (unsigned)f2bf(t1.x) | ((unsigned)f2bf(t1.y) << 16);
    w0.w = (unsigned)f2bf(t1.z) | ((unsigned)f2bf(t1.w) << 16);
    w1.x = (unsigned)f2bf(t2.x) | ((unsigned)f2bf(t2.y) << 16);
    w1.y = (unsigned)f2bf(t2.z) | ((unsigned)f2bf(t2.w) << 16);
    w1.z = (unsigned)f2bf(t3.x) | ((unsigned)f2bf(t3.y) << 16);
    w1.w = (unsigned)f2bf(t3.z) | ((unsigned)f2bf(t3.w) << 16);
    *(u32x4*)&SA[l0] = w0;                  // A(0) -> buf0
    *(u32x4*)&SA[l1] = w1;
  }
  // Outstanding now (old->new): B(0)2, A(1)4, B(1)2 = 8.

  int cbuf = 0, nbuf = 1, pbuf = 2;

  for (int k0 = 0; k0 < K_DIM; k0 += 32) {
    // step1: retire B(t); A(t)/B ds ops drained; all waves synced.
    asm volatile("s_waitcnt vmcnt(6) lgkmcnt(0)\n\ts_barrier" ::: "memory");

    int kf2 = k0 + 64;                      // tile t+2 (clamped tail)
    if (kf2 > K_DIM - 32) kf2 = K_DIM - 32;

    f32x4 nA0 = *(const f32x4*)(a0f + kf2);      // step2: A(t+2) fp32
    f32x4 nA1 = *(const f32x4*)(a0f + kf2 + 4);
    f32x4 nA2 = *(const f32x4*)(a1f + kf2);
    f32x4 nA3 = *(const f32x4*)(a1f + kf2 + 4);
    __builtin_amdgcn_sched_barrier(0);
    GLD16(b0 + kf2, &SB[pbuf * 8192 + l0]);      // step3: B(t+2)
    GLD16(b1 + kf2, &SB[pbuf * 8192 + l1]);
    __builtin_amdgcn_sched_barrier(0);

    asm volatile("s_waitcnt vmcnt(8)" ::: "memory");  // step4: A(t+1) ready
    {
      u32x4 w0, w1;                                    // step5: cvt + write
      w0.x = (unsigned)f2bf(cA0.x) | ((unsigned)f2bf(cA0.y) << 16);
      w0.y = (unsigned)f2bf(cA0.z) | ((unsigned)f2bf(cA0.w) << 16);
      w0.z = (unsigned)f2bf(cA1.x) | ((unsigned)f2bf(cA1.y) << 16);
      w0.w = (unsigned)f2bf(cA1.z) | ((unsigned)f2bf(cA1.w) << 16);
      w1.x = (unsigned)f2bf(cA2.x) | ((unsigned)f2bf(cA2.y) << 16);
      w1.y = (unsigned)f2bf(cA2.z) | ((unsigned)f2bf(cA2.w) << 16);
      w1.z = (unsigned)f2bf(cA3.x) | ((unsigned)f2bf(cA3.y) << 16);
      w1.w = (unsigned)f2bf(cA3.z) | ((unsigned)f2bf(cA3.w) << 16);
      *(u32x4*)&SA[nbuf * 8192 + l0] = w0;
      *(u32x4*)&SA[nbuf * 8192 + l1] = w1;
    }

    bf16x8 af[8], bfr[4];                   // step7: compute tile t
#pragma unroll
    for (int i = 0; i < 8; i++)
      af[i] = *(const bf16x8*)&SA[cbuf * 8192 + (wm + i * 16 + lrow) * 32 + kslot];
#pragma unroll
    for (int j = 0; j < 4; j++)
      bfr[j] = *(const bf16x8*)&SB[cbuf * 8192 + (wn + j * 16 + lrow) * 32 + kslot];

#pragma unroll
    for (int i = 0; i < 8; i++)
#pragma unroll
      for (int j = 0; j < 4; j++)
        acc[i][j] = __builtin_amdgcn_mfma_f32_16x16x32_bf16(
            af[i], bfr[j], acc[i][j], 0, 0, 0);

    cA0 = nA0; cA1 = nA1; cA2 = nA2; cA3 = nA3;  // rotate reg pipeline
    int old = cbuf; cbuf = nbuf; nbuf = pbuf; pbuf = old;
  }

  // Epilogue: C/D layout col = lane&15, row = (lane>>4)*4 + reg [m89-verified]
  // + factored-out per-column scale in fp32 (r11, harness-passed).
  float sj[4];
#pragma unroll
  for (int j = 0; j < 4; j++)
    sj[j] = S[bn * 256 + wn + j * 16 + lrow];

#pragma unroll
  for (int i = 0; i < 8; i++) {
    const int row0 = bm * 256 + wm + i * 16 + kgrp * 4;
#pragma unroll
    for (int j = 0; j < 4; j++) {
      const int col = bn * 256 + wn + j * 16 + lrow;
#pragma unroll
      for (int r = 0; r < 4; r++)
        C[(size_t)(row0 + r) * N_DIM + col] = acc[i][j][r] * sj[j];
    }
  }
}

// ---------------------------------------------------------------------------
// Fallback (only if workspace is too small for wb + cbb).
// ---------------------------------------------------------------------------
__global__ __launch_bounds__(256) void naive_kernel(
    const float* __restrict__ x, const int* __restrict__ indices,
    const float* __restrict__ cb, const float* __restrict__ scales,
    float* __restrict__ out) {
  int n = blockIdx.x * 256 + threadIdx.x;
  int m = blockIdx.y;
  if (n >= N_DIM) return;
  float s = scales[n];
  const float* xr = x + (size_t)m * IN_F;
  const int* ir = indices + (size_t)n * VPR;
  float acc = 0.f;
  for (int v = 0; v < VPR; v++) {
    int id = ir[v];
    const float* c = cb + (size_t)id * 8;
#pragma unroll
    for (int e = 0; e < 8; e++) acc += xr[v * 8 + e] * c[e];
  }
  out[(size_t)m * N_DIM + n] = acc * s;
}

extern "C" void kernel_launch(void* const* d_in, const int* in_sizes, int n_in,
                              void* d_out, int out_size, void* d_ws, size_t ws_size,
                              hipStream_t stream) {
  const float* x       = (const float*)d_in[0];   // (2,2048,11008) fp32
  const int*   indices = (const int*)d_in[1];     // (5636096,) int32
  const float* cb      = (const float*)d_in[2];   // (32768,8) fp32
  const float* scales  = (const float*)d_in[3];   // (4096,1) fp32
  float* out = (float*)d_out;                     // (2,2048,4096) fp32

  const size_t wb_elems  = (size_t)N_DIM * K_DIM;  // 45,088,768
  const size_t cbb_elems = (size_t)NCODES * VECD;  // 262,144
  const size_t need = (wb_elems + cbb_elems) * sizeof(unsigned short); // ~91 MB

  if (ws_size >= need) {
    unsigned short* wb  = (unsigned short*)d_ws;
    unsigned short* cbb = wb + wb_elems;
    cbcast_kernel<<<NCODES / 256, 256, 0, stream>>>(cb, cbb);
    wdequant_kernel<<<NVEC / 256, 256, 0, stream>>>(indices, cbb, wb);
    gemm_bt_kernel<<<(M_DIM / 256) * (N_DIM / 256), 512, 6 * 8192 * 2, stream>>>(
        x, wb, scales, out);
  } else {
    naive_kernel<<<dim3(N_DIM / 256, M_DIM), 256, 0, stream>>>(x, indices, cb,
                                                               scales, out);
  }
}